// Round 13
// baseline (182.462 us; speedup 1.0000x reference)
//
#include <hip/hip_runtime.h>

#define LN_EPS 1e-5f

typedef __attribute__((ext_vector_type(8))) short s8vec;   // 8 bf16 (MFMA A/B frag)
typedef __attribute__((ext_vector_type(4))) float f4vec;   // MFMA C/D frag

// ---- workspace layout (bytes) ----
#define OFF_WPF   0u         // gamma-folded W' BLOCKED FRAGS [12 c][4 wid][2 ks][4 n][64 lane][16B] = 384 KB
#define OFF_W1F   393216u    // W1 blocked frags [16 t][8 ks][64 lane][16 B] = 128 KB
#define OFF_U     524288u    // u[256] f32
#define OFF_C     525312u    // c[256] f32
#define OFF_UPART 526336u    // 48*256 f32 partials
#define OFF_VPART 575488u
#define OFF_PM    624640u    // per-chunk softmax max   [4096] f32
#define OFF_PS    641024u    // per-chunk softmax denom [4096] f32
#define OFF_PO    657408u    // per-chunk weighted sums [4096][256] f32 (4 MB)

#define BAR()     asm volatile("s_barrier" ::: "memory")
#define WAIT_L0() asm volatile("s_waitcnt lgkmcnt(0)" ::: "memory")

__device__ __forceinline__ unsigned short f2bf(float f) {  // RNE fp32->bf16 (finite inputs)
  unsigned int u = __float_as_uint(f);
  u += 0x7fffu + ((u >> 16) & 1u);
  return (unsigned short)(u >> 16);
}
__device__ __forceinline__ float bf2f(unsigned short h) {
  return __uint_as_float(((unsigned int)h) << 16);
}

// K0: gamma-folded W' in BLOCKED FRAG layout (W'F); W1F blocked. Unchanged from R11/R12.
__global__ void k0_prep(const float* __restrict__ Wp,
                        const float* __restrict__ gamma,
                        const float* __restrict__ beta,
                        const float* __restrict__ W1,
                        char* __restrict__ ws) {
  const int blk = blockIdx.x;
  const int n = threadIdx.x;
  if (blk < 48) {
    unsigned short* wpf = (unsigned short*)(ws + OFF_WPF);
    const int wid = n >> 6, nn = (n >> 4) & 3, lr = n & 15;   // n = output col
    const int k0 = blk * 16;
    float up = 0.f, vp = 0.f;
#pragma unroll
    for (int j = 0; j < 16; ++j) {
      const int k = k0 + j;
      const float w = Wp[k * 256 + n];          // coalesced across n
      const float wpv = gamma[k] * w;
      up += wpv;
      vp += beta[k] * w;
      const int c = k >> 6, ks = (k >> 5) & 1, lqd = (k >> 3) & 3, jj = k & 7;
      wpf[(((((c * 4 + wid) * 2 + ks) * 4 + nn) * 64) + lqd * 16 + lr) * 8 + jj] = f2bf(wpv);
    }
    ((float*)(ws + OFF_UPART))[blk * 256 + n] = up;
    ((float*)(ws + OFF_VPART))[blk * 256 + n] = vp;
  } else {
    unsigned short* w1f = (unsigned short*)(ws + OFF_W1F);
    const int d0 = (blk - 48) * 16;
    const int t = n >> 4, lre = n & 15;
#pragma unroll
    for (int jj = 0; jj < 16; ++jj) {
      const int d = d0 + jj;
      const int ks = d >> 5, lqd = (d >> 3) & 3, j = d & 7;
      w1f[(((t * 8 + ks) * 64) + lqd * 16 + lre) * 8 + j] = f2bf(W1[d * 256 + n]);
    }
  }
}

__global__ void k0_reduce(const float* __restrict__ bproj, char* __restrict__ ws) {
  const int n = threadIdx.x;
  const float* upart = (const float*)(ws + OFF_UPART);
  const float* vpart = (const float*)(ws + OFF_VPART);
  float u = 0.f, v = 0.f;
  for (int i = 0; i < 48; ++i) {
    u += upart[i * 256 + n];
    v += vpart[i * 256 + n];
  }
  ((float*)(ws + OFF_U))[n] = u;
  ((float*)(ws + OFF_C))[n] = v + bproj[n];
}

// K1: 32-ROW blocks (was 64). Rationale: 12 rounds show k1 is HBM-paced at
// ~2.7 TB/s = (per-CU x-issue per iter) / (iteration period), and the period
// is invariant under all scheduling changes. Raise the numerator instead:
// LDS 19456 B + smaller acc -> 4-6 independent blocks/CU (was 2) = 2-3x the
// independent x-streams and barrier groups per CU (the R1->R2 lever, the only
// one that ever moved this kernel). B-path (W'F direct-global) unchanged.
__global__ __launch_bounds__(256)
void k1_main(const float* __restrict__ x,
             const float* __restrict__ b1,
             const float* __restrict__ W2,
             char* __restrict__ ws) {
  __shared__ __align__(16) char sm[19456];
  // phase 1: A dbuf = sm + p*4096, bf16 [32][64], XOR (r&7)<<4
  char* const sm_h = sm;                       // ph2/3: bf16 [32][256], XOR (r&7)<<4 (alias)
  float* const f_b1 = (float*)(sm + 16384);    // [256]
  float* const f_w2 = (float*)(sm + 17408);    // [256]
  float* const f_lp = (float*)(sm + 18432);    // [32][4]
  float* const f_lg = (float*)(sm + 18944);    // [32]
  float* const f_e  = (float*)(sm + 19072);    // [32]
  float* const f_mu = (float*)(sm + 19200);    // [32]
  float* const f_iv = (float*)(sm + 19328);    // [32]  (ends at 19456)

  const int tid  = threadIdx.x;
  const int lane = tid & 63;
  const int wid  = tid >> 6;     // wave col 0..3 (64 N-cols each; waves share all 32 M-rows)
  const int lr = lane & 15;
  const int lq = lane >> 4;

  const int arow = tid >> 3;     // staging A: 8 threads per row, 8 floats each
  const int aq   = tid & 7;
  const float* xrow = x + (size_t)(blockIdx.x * 32 + arow) * 768 + aq * 8;

  const char* wpf = (const char*)ws + OFF_WPF + wid * 8192 + lane * 16;

  const f4vec fz = {0.f, 0.f, 0.f, 0.f};
  f4vec acc[2][4];
#pragma unroll
  for (int m = 0; m < 2; ++m)
#pragma unroll
    for (int n = 0; n < 4; ++n) acc[m][n] = fz;

  float s1 = 0.f, s2 = 0.f;
  float xvA[8], xvB[8];                  // ping-pong x prefetch, distance 2

  auto loadx = [&](float (&xv)[8], int c) {
#pragma unroll
    for (int j = 0; j < 2; ++j) {
      const float4 t = *(const float4*)(xrow + c * 64 + j * 4);
      xv[4*j+0] = t.x; xv[4*j+1] = t.y; xv[4*j+2] = t.z; xv[4*j+3] = t.w;
    }
  };
  auto packA = [&](const float (&xv)[8], int p) {  // sanitize, LN sums, bf16 -> abuf[p]
    unsigned int pk[4];
#pragma unroll
    for (int j = 0; j < 8; ++j) {
      float f = xv[j];
      if ((__float_as_uint(f) & 0x7f800000u) == 0x7f800000u) f = 0.f;  // nan/inf -> 0
      s1 += f; s2 += f * f;
      const unsigned int hb = f2bf(f);
      if ((j & 1) == 0) pk[j >> 1] = hb; else pk[j >> 1] |= hb << 16;
    }
    *(int4*)(sm + p * 4096 + ((arow * 128 + aq * 16) ^ ((arow & 7) << 4))) =
        make_int4((int)pk[0], (int)pk[1], (int)pk[2], (int)pk[3]);
  };
  auto mfmaStep = [&](int c) {           // B direct-global + A from abuf[c&1]
    s8vec bfv[8];
#pragma unroll
    for (int ks = 0; ks < 2; ++ks)
#pragma unroll
      for (int n = 0; n < 4; ++n)
        bfv[ks * 4 + n] =
            *(const s8vec*)(wpf + (size_t)(c * 32768 + ks * 4096 + n * 1024));
#pragma unroll
    for (int ks = 0; ks < 2; ++ks) {
      const int kb = (ks * 32 + lq * 8) * 2;
      s8vec af[2];
#pragma unroll
      for (int m = 0; m < 2; ++m) {
        const int row = m * 16 + lr;
        af[m] = *(const s8vec*)(sm + (c & 1) * 4096 + ((row * 128 + kb) ^ ((row & 7) << 4)));
      }
#pragma unroll
      for (int m = 0; m < 2; ++m)
#pragma unroll
        for (int n = 0; n < 4; ++n)
          acc[m][n] = __builtin_amdgcn_mfma_f32_16x16x32_bf16(af[m], bfv[ks * 4 + n], acc[m][n], 0, 0, 0);
    }
  };

  // ---- prologue ----
  loadx(xvA, 0);
  loadx(xvB, 1);
  packA(xvA, 0);                         // chunk 0 -> buf 0
  loadx(xvA, 2);
  WAIT_L0(); BAR();

  // ---- main loop: per iter {pack c+1 | MFMA c | refill}, 1 barrier ----
  for (int cc = 0; cc < 12; cc += 2) {
    // even iter: MFMA cc (buf0), pack cc+1 (from xvB -> buf1), refill xvB<-cc+3
    packA(xvB, 1);
    if (cc + 3 <= 11) loadx(xvB, cc + 3);
    mfmaStep(cc);
    WAIT_L0(); BAR();
    // odd iter: MFMA cc+1 (buf1), pack cc+2 (from xvA -> buf0), refill xvA<-cc+4
    if (cc + 2 <= 11) packA(xvA, 0);
    if (cc + 4 <= 11) loadx(xvA, cc + 4);
    mfmaStep(cc + 1);
    WAIT_L0(); BAR();
  }

  // ---- LN row stats (reduce the 8 staging lanes of each row) ----
  s1 += __shfl_xor(s1, 1); s1 += __shfl_xor(s1, 2); s1 += __shfl_xor(s1, 4);
  s2 += __shfl_xor(s2, 1); s2 += __shfl_xor(s2, 2); s2 += __shfl_xor(s2, 4);
  if (aq == 0) {
    const float mu = s1 * (1.f / 768.f);
    float var = s2 * (1.f / 768.f) - mu * mu;
    var = fmaxf(var, 0.f);
    f_mu[arow] = mu;
    f_iv[arow] = rsqrtf(var + LN_EPS);
  }
  f_b1[tid] = b1[tid];
  f_w2[tid] = W2[tid];
  float u4[4], c4[4];
#pragma unroll
  for (int n = 0; n < 4; ++n) {
    u4[n] = ((const float*)(ws + OFF_U))[wid * 64 + n * 16 + lr];
    c4[n] = ((const float*)(ws + OFF_C))[wid * 64 + n * 16 + lr];
  }
  WAIT_L0();                             // mu/iv/b1/w2 ds_writes drained
  BAR();                                 // all A-dbuf reads retired (h aliases it)

  // ---- finalize h = inv*(g - mu*u) + c, write bf16 h tile [32][512B] ----
#pragma unroll
  for (int m = 0; m < 2; ++m) {
#pragma unroll
    for (int i = 0; i < 4; ++i) {
      const int rl = m * 16 + lq * 4 + i;
      const float mu  = f_mu[rl];
      const float inv = f_iv[rl];
      const int sw = (rl & 7) << 4;
#pragma unroll
      for (int n = 0; n < 4; ++n) {
        const int cd = wid * 64 + n * 16 + lr;
        const float h = inv * (acc[m][n][i] - mu * u4[n]) + c4[n];
        *(unsigned short*)(sm_h + ((rl * 512 + cd * 2) ^ sw)) = f2bf(h);
      }
    }
  }
  WAIT_L0();                             // h writes drained
  BAR();                                 // sm_h visible; read-only from here

  // ---- phase 2 (operand-swapped, barrier-free): S^T = W1^T @ h^T ----
  const char* w1f = (const char*)ws + OFF_W1F;
  f4vec acc2[4][2];                      // [et][rt]
#pragma unroll
  for (int m = 0; m < 4; ++m)
#pragma unroll
    for (int n = 0; n < 2; ++n) acc2[m][n] = fz;

#pragma unroll
  for (int ks = 0; ks < 8; ++ks) {       // K = d, 8 steps of 32
    s8vec af[4], bf[2];
#pragma unroll
    for (int et = 0; et < 4; ++et)
      af[et] = *(const s8vec*)(w1f + (((wid * 4 + et) * 8 + ks) * 64 + lane) * 16);
#pragma unroll
    for (int rt = 0; rt < 2; ++rt) {
      const int r = rt * 16 + lr;
      bf[rt] = *(const s8vec*)(sm_h + ((r * 512 + ks * 64 + lq * 16) ^ ((r & 7) << 4)));
    }
#pragma unroll
    for (int et = 0; et < 4; ++et)
#pragma unroll
      for (int rt = 0; rt < 2; ++rt)
        acc2[et][rt] = __builtin_amdgcn_mfma_f32_16x16x32_bf16(af[et], bf[rt], acc2[et][rt], 0, 0, 0);
  }

  // ---- logits: z=S+b1 -> tanh -> * W2, reduce over e ----
  float lp[2] = {0.f, 0.f};
#pragma unroll
  for (int et = 0; et < 4; ++et) {
#pragma unroll
    for (int i = 0; i < 4; ++i) {
      const int e = wid * 64 + et * 16 + lq * 4 + i;
      const float b1v = f_b1[e];
      const float w2v = f_w2[e];
#pragma unroll
      for (int rt = 0; rt < 2; ++rt) {
        float z = acc2[et][rt][i] + b1v;
        z = fminf(fmaxf(z, -15.f), 15.f);
        const float e2 = __expf(2.f * z);
        const float a = (e2 - 1.f) / (e2 + 1.f);   // tanh
        lp[rt] += a * w2v;
      }
    }
  }
#pragma unroll
  for (int rt = 0; rt < 2; ++rt) {
    float t = lp[rt];
    t += __shfl_xor(t, 16);
    t += __shfl_xor(t, 32);              // sum the 4 lq-groups (wave's 64 e's)
    if (lq == 0) f_lp[(rt * 16 + lr) * 4 + wid] = t;
  }
  __syncthreads();
  if (tid < 32)
    f_lg[tid] = f_lp[tid*4+0] + f_lp[tid*4+1] + f_lp[tid*4+2] + f_lp[tid*4+3];
  __syncthreads();

  // ---- phase 3: chunk-local softmax partials + pooled partial vector ----
  float mx = -1e30f;
  for (int r = 0; r < 32; ++r) mx = fmaxf(mx, f_lg[r]);    // LDS broadcast, uniform
  if (tid < 32) f_e[tid] = __expf(f_lg[tid] - mx);
  __syncthreads();

  {
    const int d = tid;
    float o = 0.f;
    for (int r = 0; r < 32; ++r) {
      const float ev = f_e[r];
      const unsigned short hb =
          *(const unsigned short*)(sm_h + ((r * 512 + d * 2) ^ ((r & 7) << 4)));
      o += ev * bf2f(hb);
    }
    ((float*)(ws + OFF_PO))[blockIdx.x * 256 + d] = o;
  }
  if (tid == 0) {
    float s = 0.f;
    for (int r = 0; r < 32; ++r) s += f_e[r];
    ((float*)(ws + OFF_PS))[blockIdx.x] = s;
    ((float*)(ws + OFF_PM))[blockIdx.x] = mx;
  }
}

// K2: combine 64 chunk-partials per batch element (online-softmax merge).
__global__ void k2_combine(const char* __restrict__ ws, float* __restrict__ out) {
  const int b = blockIdx.x;
  const int d = threadIdx.x;
  const float* pm = (const float*)(ws + OFF_PM) + b * 64;
  const float* ps = (const float*)(ws + OFF_PS) + b * 64;
  const float* po = (const float*)(ws + OFF_PO) + (size_t)b * 64 * 256;
  float mx = -1e30f;
  for (int c = 0; c < 64; ++c) mx = fmaxf(mx, pm[c]);
  float num = 0.f, den = 0.f;
  for (int c = 0; c < 64; ++c) {
    const float al = __expf(pm[c] - mx);
    den += al * ps[c];
    num += al * po[c * 256 + d];
  }
  out[b * 256 + d] = num / den;
}

extern "C" void kernel_launch(void* const* d_in, const int* in_sizes, int n_in,
                              void* d_out, int out_size, void* d_ws, size_t ws_size,
                              hipStream_t stream) {
  const float* x     = (const float*)d_in[0];
  const float* gamma = (const float*)d_in[1];
  const float* beta  = (const float*)d_in[2];
  const float* Wp    = (const float*)d_in[3];
  const float* bproj = (const float*)d_in[4];
  const float* W1    = (const float*)d_in[5];
  const float* b1    = (const float*)d_in[6];
  const float* W2    = (const float*)d_in[7];
  // d_in[8] = b2 scalar: softmax is shift-invariant -> drops out exactly.
  char* ws = (char*)d_ws;   // needs ~4.85 MB
  float* out = (float*)d_out;

  k0_prep   <<<dim3(64),   dim3(256), 0, stream>>>(Wp, gamma, beta, W1, ws);
  k0_reduce <<<dim3(1),    dim3(256), 0, stream>>>(bproj, ws);
  k1_main   <<<dim3(4096), dim3(256), 0, stream>>>(x, b1, W2, ws);
  k2_combine<<<dim3(64),   dim3(256), 0, stream>>>(ws, out);
}

// Round 14
// 154.067 us; speedup vs baseline: 1.1843x; 1.1843x over previous
//
#include <hip/hip_runtime.h>

#define LN_EPS 1e-5f

typedef __attribute__((ext_vector_type(8))) short s8vec;   // 8 bf16 (MFMA A/B frag)
typedef __attribute__((ext_vector_type(4))) float f4vec;   // MFMA C/D frag

// ---- workspace layout (bytes); total ~2.74 MB ----
#define OFF_WPT   0u         // gamma-folded W_projT, PRE-SWIZZLED [12 chunks][256 n][128 B]
#define OFF_W1F   393216u    // W1 blocked frag layout [16 t][8 ks][64 lane][16 B] = 128 KB
#define OFF_U     524288u    // u[256] f32 : sum_k gamma_k W[k][d]
#define OFF_C     525312u    // c[256] f32 : sum_k beta_k W[k][d] + b_proj[d]
#define OFF_UPART 526336u    // 48*256 f32 partials
#define OFF_VPART 575488u
#define OFF_PM    624640u    // per-chunk softmax max   [2048] f32
#define OFF_PS    632832u    // per-chunk softmax denom [2048] f32
#define OFF_PO    641024u    // per-chunk weighted sums [2048][256] f32

#define BAR()     asm volatile("s_barrier" ::: "memory")
#define WAIT_V4() asm volatile("s_waitcnt vmcnt(4) lgkmcnt(0)" ::: "memory")
#define WAIT_V0() asm volatile("s_waitcnt vmcnt(0) lgkmcnt(0)" ::: "memory")
#define WAIT_L0() asm volatile("s_waitcnt lgkmcnt(0)" ::: "memory")
// Pin issue order so counted vmcnt is valid: gll16s must stay the OLDEST
// outstanding vmem ops (round-3 lesson; race otherwise).
#define ORDER_FENCE() do { asm volatile("" ::: "memory"); \
                           __builtin_amdgcn_sched_barrier(0); } while (0)

__device__ __forceinline__ unsigned short f2bf(float f) {  // RNE fp32->bf16 (finite inputs)
  unsigned int u = __float_as_uint(f);
  u += 0x7fffu + ((u >> 16) & 1u);
  return (unsigned short)(u >> 16);
}
__device__ __forceinline__ float bf2f(unsigned short h) {
  return __uint_as_float(((unsigned int)h) << 16);
}
__device__ __forceinline__ void gll16(const void* g, void* l) {  // async global->LDS, 16 B/lane
  __builtin_amdgcn_global_load_lds(
      (const __attribute__((address_space(1))) unsigned int*)g,
      (__attribute__((address_space(3))) unsigned int*)l, 16, 0, 0);
}

// K0: W'T pre-swizzled (round-4 layout). W1 emitted as BLOCKED FRAG layout
// W1F[t][ks][lane][16B]: lane(lr,lq) holds W1[d=ks*32+lq*8 .. +8][e=t*16+lr]
// so phase-2 A-frag loads are 64 consecutive 16B lanes (one 1KB transaction).
__global__ void k0_prep(const float* __restrict__ Wp,
                        const float* __restrict__ gamma,
                        const float* __restrict__ beta,
                        const float* __restrict__ W1,
                        char* __restrict__ ws) {
  const int blk = blockIdx.x;
  const int n = threadIdx.x;
  if (blk < 48) {
    unsigned short* wpt = (unsigned short*)(ws + OFF_WPT);
    const int sw = (n & 7) << 4;
    const int k0 = blk * 16;
    float up = 0.f, vp = 0.f;
#pragma unroll
    for (int j = 0; j < 16; ++j) {
      const int k = k0 + j;
      const float w = Wp[k * 256 + n];          // coalesced across n
      const float wpv = gamma[k] * w;
      up += wpv;
      vp += beta[k] * w;
      const int c = k >> 6, kc = k & 63;
      wpt[c * 16384 + n * 64 + ((((kc * 2) ^ sw)) >> 1)] = f2bf(wpv);
    }
    ((float*)(ws + OFF_UPART))[blk * 256 + n] = up;
    ((float*)(ws + OFF_VPART))[blk * 256 + n] = vp;
  } else {
    unsigned short* w1f = (unsigned short*)(ws + OFF_W1F);
    const int d0 = (blk - 48) * 16;
    const int t = n >> 4, lre = n & 15;         // n = e
#pragma unroll
    for (int jj = 0; jj < 16; ++jj) {
      const int d = d0 + jj;
      const int ks = d >> 5, lqd = (d >> 3) & 3, j = d & 7;
      w1f[(((t * 8 + ks) * 64) + lqd * 16 + lre) * 8 + j] = f2bf(W1[d * 256 + n]);
    }
  }
}

__global__ void k0_reduce(const float* __restrict__ bproj, char* __restrict__ ws) {
  const int n = threadIdx.x;
  const float* upart = (const float*)(ws + OFF_UPART);
  const float* vpart = (const float*)(ws + OFF_VPART);
  float u = 0.f, v = 0.f;
  for (int i = 0; i < 48; ++i) {
    u += upart[i * 256 + n];
    v += vpart[i * 256 + n];
  }
  ((float*)(ws + OFF_U))[n] = u;
  ((float*)(ws + OFF_C))[n] = v + bproj[n];
}

// K1: round-4 phase-1 body; LDS packed to 40960 B:
//   [0,8K)   phase-1 A tile   | phase-2/3 alias: b1,w2,lp,lg,e,mu,inv
//   [8K,40K) phase-1 B tile   | phase-2/3 h tile
// __launch_bounds__(256,2): best-measured config (R9, 154.9 us). The (256,4)
// variant spilled (VGPR cap 64 -> 960 MB scratch, R8); all scheduling
// variants (R4/R6/R11/R12) and tile variants (R5/R7/R13) were null or worse.
__global__ __launch_bounds__(256, 2)
void k1_main(const float* __restrict__ x,
             const float* __restrict__ b1,
             const float* __restrict__ W2,
             char* __restrict__ ws) {
  __shared__ __align__(16) char sm[40960];
  char* const sm_a = sm;                       // bf16 [64][64],  XOR (r&7)<<4
  char* const sm_b = sm + 8192;                // bf16 [256][64], XOR (n&7)<<4
  char* const sm_h = sm + 8192;                // bf16 [64][256], XOR (r&7)<<4 (alias)
  float* const f_b1 = (float*)sm;              // [256]  (alias of sm_a, ph2/3)
  float* const f_w2 = (float*)(sm + 1024);     // [256]
  float* const f_lp = (float*)(sm + 2048);     // [64][4]
  float* const f_lg = (float*)(sm + 3072);     // [64]
  float* const f_e  = (float*)(sm + 3328);     // [64]
  float* const f_mu = (float*)(sm + 3584);     // [64]
  float* const f_iv = (float*)(sm + 3840);     // [64]

  const int tid  = threadIdx.x;
  const int lane = tid & 63;
  const int wid  = tid >> 6;     // wave col 0..3 (64 N-cols each; waves share all 64 M-rows)
  const int lr = lane & 15;
  const int lq = lane >> 4;

  const int arow = tid >> 2;     // staging A: 4 threads per row
  const int aq   = tid & 3;
  const float* xrow = x + (size_t)(blockIdx.x * 64 + arow) * 768 + aq * 16;

  const char* bsrc = (const char*)ws + OFF_WPT + wid * 8192 + lane * 16;
  char*       bdst = sm_b + wid * 8192 + lane * 16;

  const f4vec fz = {0.f, 0.f, 0.f, 0.f};
  f4vec acc[4][4];
#pragma unroll
  for (int m = 0; m < 4; ++m)
#pragma unroll
    for (int n = 0; n < 4; ++n) acc[m][n] = fz;

  float s1 = 0.f, s2 = 0.f;
  float4 vaA[4], vaB[4];                 // ping-pong x prefetch, distance 2
#pragma unroll
  for (int j = 0; j < 4; ++j) vaA[j] = *(const float4*)(xrow + 0 * 64 + j * 4);
#pragma unroll
  for (int j = 0; j < 4; ++j) vaB[j] = *(const float4*)(xrow + 1 * 64 + j * 4);

  // Phase-1 iteration body (round-4, proven). va: chunk c, refilled with c+2.
  auto p1body = [&](int c, float4 (&va)[4], bool pf) {
    // B: async linear copy of pre-swizzled W'T chunk (L2-resident)
#pragma unroll
    for (int s = 0; s < 8; ++s) gll16(bsrc + c * 32768 + s * 1024, bdst + s * 1024);
    ORDER_FENCE();                       // gll16s stay the OLDEST vmem ops
    // A: sanitize, LN sums, pack bf16, swizzled LDS write
    float v[16];
#pragma unroll
    for (int j = 0; j < 4; ++j) {
      v[4*j+0] = va[j].x; v[4*j+1] = va[j].y; v[4*j+2] = va[j].z; v[4*j+3] = va[j].w;
    }
    unsigned int pk[8];
#pragma unroll
    for (int j = 0; j < 16; ++j) {
      float f = v[j];
      if ((__float_as_uint(f) & 0x7f800000u) == 0x7f800000u) f = 0.f;  // nan/inf -> 0
      s1 += f; s2 += f * f;
      const unsigned int hb = f2bf(f);
      if ((j & 1) == 0) pk[j >> 1] = hb; else pk[j >> 1] |= hb << 16;
    }
    {
      const int base = arow * 128 + aq * 32;
      const int sw = (arow & 7) << 4;
      *(int4*)(sm_a + ((base     ) ^ sw)) = make_int4((int)pk[0], (int)pk[1], (int)pk[2], (int)pk[3]);
      *(int4*)(sm_a + ((base + 16) ^ sw)) = make_int4((int)pk[4], (int)pk[5], (int)pk[6], (int)pk[7]);
    }
    // prefetch chunk c+2 into the SAME named array (stays in flight across barrier)
    if (pf) {
#pragma unroll
      for (int j = 0; j < 4; ++j) va[j] = *(const float4*)(xrow + (c + 2) * 64 + j * 4);
    }
    if (pf) WAIT_V4(); else WAIT_V0();   // B-gll + A ds_writes drained; x prefetch flying
    BAR();
    // MFMA: 2 k-steps of 32
#pragma unroll
    for (int ks = 0; ks < 2; ++ks) {
      const int kb = (ks * 32 + lq * 8) * 2;
      s8vec af[4], bfv[4];
#pragma unroll
      for (int m = 0; m < 4; ++m) {
        const int row = m * 16 + lr;
        af[m] = *(const s8vec*)(sm_a + ((row * 128 + kb) ^ ((row & 7) << 4)));
      }
#pragma unroll
      for (int n = 0; n < 4; ++n) {
        const int row = wid * 64 + n * 16 + lr;
        bfv[n] = *(const s8vec*)(sm_b + ((row * 128 + kb) ^ ((row & 7) << 4)));
      }
#pragma unroll
      for (int m = 0; m < 4; ++m)
#pragma unroll
        for (int n = 0; n < 4; ++n)
          acc[m][n] = __builtin_amdgcn_mfma_f32_16x16x32_bf16(af[m], bfv[n], acc[m][n], 0, 0, 0);
    }
    BAR();                               // reads retired (reg-consumed) before next writes
  };

  for (int cc = 0; cc < 12; cc += 2) {
    p1body(cc,     vaA, cc + 2 < 12);
    p1body(cc + 1, vaB, cc + 3 < 12);
  }

  // ---- LN row stats (reduce the 4 staging lanes of each row) ----
  s1 += __shfl_xor(s1, 1); s1 += __shfl_xor(s1, 2);
  s2 += __shfl_xor(s2, 1); s2 += __shfl_xor(s2, 2);
  if (aq == 0) {
    const float mu = s1 * (1.f / 768.f);
    float var = s2 * (1.f / 768.f) - mu * mu;
    var = fmaxf(var, 0.f);
    f_mu[arow] = mu;
    f_iv[arow] = rsqrtf(var + LN_EPS);
  }
  // stage b1/W2 into the sm_a alias (sm_a dead after loop-final barrier)
  f_b1[tid] = b1[tid];
  f_w2[tid] = W2[tid];
  // per-lane u,c for this thread's 4 output cols (replaces sm_u/sm_c arrays)
  float u4[4], c4[4];
#pragma unroll
  for (int n = 0; n < 4; ++n) {
    u4[n] = ((const float*)(ws + OFF_U))[wid * 64 + n * 16 + lr];
    c4[n] = ((const float*)(ws + OFF_C))[wid * 64 + n * 16 + lr];
  }
  WAIT_L0();                             // mu/iv/b1/w2 ds_writes drained
  BAR();

  // ---- finalize h = inv*(g - mu*u) + c, write bf16 h tile (into union) ----
#pragma unroll
  for (int m = 0; m < 4; ++m) {
#pragma unroll
    for (int i = 0; i < 4; ++i) {
      const int rl = m * 16 + lq * 4 + i;
      const float mu  = f_mu[rl];
      const float inv = f_iv[rl];
      const int sw = (rl & 7) << 4;
#pragma unroll
      for (int n = 0; n < 4; ++n) {
        const int cd = wid * 64 + n * 16 + lr;
        const float h = inv * (acc[m][n][i] - mu * u4[n]) + c4[n];
        *(unsigned short*)(sm_h + ((rl * 512 + cd * 2) ^ sw)) = f2bf(h);
      }
    }
  }
  WAIT_L0();                             // h writes drained
  BAR();                                 // sm_h visible; read-only from here

  // ---- phase 2 (operand-swapped, barrier-free): S^T = W1^T @ h^T ----
  // A-frags: W1F blocked global (lane-consecutive 1KB loads, L2-hot).
  // B-frags: h^T from sm_h — identical address pattern to phase-1 A reads.
  const char* w1f = (const char*)ws + OFF_W1F;
  f4vec acc2[4][4];                      // [et][rt]: rows e (wave's 64), cols r
#pragma unroll
  for (int m = 0; m < 4; ++m)
#pragma unroll
    for (int n = 0; n < 4; ++n) acc2[m][n] = fz;

#pragma unroll
  for (int ks = 0; ks < 8; ++ks) {       // K = d, 8 steps of 32
    s8vec af[4], bf[4];
#pragma unroll
    for (int et = 0; et < 4; ++et)
      af[et] = *(const s8vec*)(w1f + (((wid * 4 + et) * 8 + ks) * 64 + lane) * 16);
#pragma unroll
    for (int rt = 0; rt < 4; ++rt) {
      const int r = rt * 16 + lr;
      bf[rt] = *(const s8vec*)(sm_h + ((r * 512 + ks * 64 + lq * 16) ^ ((r & 7) << 4)));
    }
#pragma unroll
    for (int et = 0; et < 4; ++et)
#pragma unroll
      for (int rt = 0; rt < 4; ++rt)
        acc2[et][rt] = __builtin_amdgcn_mfma_f32_16x16x32_bf16(af[et], bf[rt], acc2[et][rt], 0, 0, 0);
  }

  // ---- logits: z=S+b1 -> tanh -> * W2, reduce over e ----
  float lp[4] = {0.f, 0.f, 0.f, 0.f};
#pragma unroll
  for (int et = 0; et < 4; ++et) {
#pragma unroll
    for (int i = 0; i < 4; ++i) {
      const int e = wid * 64 + et * 16 + lq * 4 + i;
      const float b1v = f_b1[e];
      const float w2v = f_w2[e];
#pragma unroll
      for (int rt = 0; rt < 4; ++rt) {
        float z = acc2[et][rt][i] + b1v;
        z = fminf(fmaxf(z, -15.f), 15.f);
        const float e2 = __expf(2.f * z);
        const float a = (e2 - 1.f) / (e2 + 1.f);   // tanh
        lp[rt] += a * w2v;
      }
    }
  }
#pragma unroll
  for (int rt = 0; rt < 4; ++rt) {
    float t = lp[rt];
    t += __shfl_xor(t, 16);
    t += __shfl_xor(t, 32);              // sum the 4 lq-groups (wave's 64 e's)
    if (lq == 0) f_lp[(rt * 16 + lr) * 4 + wid] = t;
  }
  __syncthreads();
  if (tid < 64)
    f_lg[tid] = f_lp[tid*4+0] + f_lp[tid*4+1] + f_lp[tid*4+2] + f_lp[tid*4+3];
  __syncthreads();

  // ---- phase 3: chunk-local softmax partials + pooled partial vector ----
  float mx = -1e30f;
  for (int r = 0; r < 64; ++r) mx = fmaxf(mx, f_lg[r]);    // LDS broadcast, uniform
  if (tid < 64) f_e[tid] = __expf(f_lg[tid] - mx);
  __syncthreads();

  {
    const int d = tid;
    float o = 0.f;
    for (int r = 0; r < 64; ++r) {
      const float ev = f_e[r];
      const unsigned short hb =
          *(const unsigned short*)(sm_h + ((r * 512 + d * 2) ^ ((r & 7) << 4)));
      o += ev * bf2f(hb);
    }
    ((float*)(ws + OFF_PO))[blockIdx.x * 256 + d] = o;
  }
  if (tid == 0) {
    float s = 0.f;
    for (int r = 0; r < 64; ++r) s += f_e[r];
    ((float*)(ws + OFF_PS))[blockIdx.x] = s;
    ((float*)(ws + OFF_PM))[blockIdx.x] = mx;
  }
}

// K2: combine 32 chunk-partials per batch element (online-softmax merge).
__global__ void k2_combine(const char* __restrict__ ws, float* __restrict__ out) {
  const int b = blockIdx.x;
  const int d = threadIdx.x;
  const float* pm = (const float*)(ws + OFF_PM) + b * 32;
  const float* ps = (const float*)(ws + OFF_PS) + b * 32;
  const float* po = (const float*)(ws + OFF_PO) + (size_t)b * 32 * 256;
  float mx = -1e30f;
  for (int c = 0; c < 32; ++c) mx = fmaxf(mx, pm[c]);
  float num = 0.f, den = 0.f;
  for (int c = 0; c < 32; ++c) {
    const float al = __expf(pm[c] - mx);
    den += al * ps[c];
    num += al * po[c * 256 + d];
  }
  out[b * 256 + d] = num / den;
}

extern "C" void kernel_launch(void* const* d_in, const int* in_sizes, int n_in,
                              void* d_out, int out_size, void* d_ws, size_t ws_size,
                              hipStream_t stream) {
  const float* x     = (const float*)d_in[0];
  const float* gamma = (const float*)d_in[1];
  const float* beta  = (const float*)d_in[2];
  const float* Wp    = (const float*)d_in[3];
  const float* bproj = (const float*)d_in[4];
  const float* W1    = (const float*)d_in[5];
  const float* b1    = (const float*)d_in[6];
  const float* W2    = (const float*)d_in[7];
  // d_in[8] = b2 scalar: softmax is shift-invariant -> drops out exactly.
  char* ws = (char*)d_ws;   // needs ~2.74 MB
  float* out = (float*)d_out;

  k0_prep   <<<dim3(64),   dim3(256), 0, stream>>>(Wp, gamma, beta, W1, ws);
  k0_reduce <<<dim3(1),    dim3(256), 0, stream>>>(bproj, ws);
  k1_main   <<<dim3(2048), dim3(256), 0, stream>>>(x, b1, W2, ws);
  k2_combine<<<dim3(64),   dim3(256), 0, stream>>>(ws, out);
}